// Round 2
// baseline (564.231 us; speedup 1.0000x reference)
//
#include <hip/hip_runtime.h>
#include <stdint.h>
#include <stddef.h>

// Problem constants: B=2, S=2048, H=2048, NH=16, HD=128, BS=256
constexpr int B_ = 2;
constexpr int S_ = 2048;
constexpr int H_ = 2048;
constexpr int NH_ = 16;
constexpr int HD_ = 128;
constexpr int BS_ = 256;
constexpr float SCALE_ = 0.08838834764831845f;  // 1/sqrt(128)

typedef __bf16 bf16x8 __attribute__((ext_vector_type(8)));
typedef float floatx4 __attribute__((ext_vector_type(4)));
typedef uint16_t u16x8 __attribute__((ext_vector_type(8)));

static __device__ __forceinline__ bf16x8 ld16(const uint16_t* p) {
    return __builtin_bit_cast(bf16x8, *reinterpret_cast<const uint4*>(p));
}
static __device__ __forceinline__ uint16_t f2b(float f) {
    return __builtin_bit_cast(uint16_t, (__bf16)f);  // RNE fptrunc
}

// 8 elems from fp32 (convert) or bf16 source -> packed bf16 uint4.
template <bool F32>
static __device__ __forceinline__ uint4 ldrow(const void* base, size_t eoff) {
    if constexpr (F32) {
        const float* p = (const float*)base + eoff;
        const float4 lo = *reinterpret_cast<const float4*>(p);
        const float4 hi = *reinterpret_cast<const float4*>(p + 4);
        u16x8 k;
        k[0] = f2b(lo.x); k[1] = f2b(lo.y); k[2] = f2b(lo.z); k[3] = f2b(lo.w);
        k[4] = f2b(hi.x); k[5] = f2b(hi.y); k[6] = f2b(hi.z); k[7] = f2b(hi.w);
        return __builtin_bit_cast(uint4, k);
    } else {
        return *reinterpret_cast<const uint4*>((const uint16_t*)base + eoff);
    }
}

// Async global->LDS, 16B per lane. LDS dest = wave-uniform base + lane*16.
static __device__ __forceinline__ void gld_lds16(const uint16_t* g, const uint4* lds_wave_base) {
    __builtin_amdgcn_global_load_lds(
        (const __attribute__((address_space(1))) uint32_t*)g,
        (__attribute__((address_space(3))) uint32_t*)lds_wave_base,
        16, 0, 0);
}

// fp32 -> bf16 pack, 8 elems/thread.
__global__ __launch_bounds__(256) void cvt_kernel(const float* __restrict__ src,
                                                  uint16_t* __restrict__ dst) {
    const size_t i = (size_t)blockIdx.x * 256 + threadIdx.x;
    reinterpret_cast<uint4*>(dst)[i] = ldrow<true>(src, i * 8);
}

// 4 weights in one dispatch (blockIdx.y selects).
__global__ __launch_bounds__(256) void cvt4_kernel(const float* __restrict__ s0,
                                                   const float* __restrict__ s1,
                                                   const float* __restrict__ s2,
                                                   const float* __restrict__ s3,
                                                   uint16_t* __restrict__ d0,
                                                   uint16_t* __restrict__ d1,
                                                   uint16_t* __restrict__ d2,
                                                   uint16_t* __restrict__ d3) {
    const int w = blockIdx.y;
    const float* src = (w == 0) ? s0 : (w == 1) ? s1 : (w == 2) ? s2 : s3;
    uint16_t* dst = (w == 0) ? d0 : (w == 1) ? d1 : (w == 2) ? d2 : d3;
    const size_t i = (size_t)blockIdx.x * 256 + threadIdx.x;
    reinterpret_cast<uint4*>(dst)[i] = ldrow<true>(src, i * 8);
}

// ---------------------------------------------------------------------------
// GEMM core (round-0 structure, reverted): C[M x N] = A[M x K] * W[N x K]^T,
// bf16 LDS tiles via async global_load_lds, XOR-swizzled 16B chunks.
// Tile 128x128, BK=64, 4 waves, 32KB LDS -> ~2.5-3 wg/CU implicit overlap.
// (Round-1 lesson: explicit 2-deep pipeline at 128²/4-wave loses to the
//  multi-wg implicit overlap — m232 open quadrant confirmed on this problem.)
// ---------------------------------------------------------------------------
template <bool TSTORE, bool OF32>
static __device__ __forceinline__ void gemm_body(const uint16_t* __restrict__ Abase,
                                                 const uint16_t* __restrict__ Wbase,
                                                 void* __restrict__ C,
                                                 int m0, int n0, uint4* As, uint4* Bs) {
    constexpr int K = H_;
    constexpr int N = H_;
    const int tid = threadIdx.x;
    const int lane = tid & 63;
    const int wave = tid >> 6;
    const int col = lane & 15;
    const int quad = lane >> 4;
    const int wr = (wave >> 1) * 64;
    const int wc = (wave & 1) * 64;

    floatx4 acc[4][4] = {};

    for (int kb = 0; kb < K; kb += 64) {
        __syncthreads();  // prev tile's readers done before LDS overwritten
#pragma unroll
        for (int i = 0; i < 4; ++i) {
            const int L = tid + i * 256;
            const int row = L >> 3;
            const int gch = (L & 7) ^ (row & 7);
            gld_lds16(Abase + (size_t)row * K + kb + gch * 8, &As[i * 256 + wave * 64]);
            gld_lds16(Wbase + (size_t)row * K + kb + gch * 8, &Bs[i * 256 + wave * 64]);
        }
        __syncthreads();  // drains vmcnt (async LDS stores)
#pragma unroll
        for (int ks = 0; ks < 2; ++ks) {
            bf16x8 af[4], bfr[4];
            const int ch = ks * 4 + quad;
#pragma unroll
            for (int mt = 0; mt < 4; ++mt) {
                const int m = wr + mt * 16 + col;
                af[mt] = __builtin_bit_cast(bf16x8, As[m * 8 + (ch ^ (m & 7))]);
            }
#pragma unroll
            for (int nt = 0; nt < 4; ++nt) {
                const int n = wc + nt * 16 + col;
                bfr[nt] = __builtin_bit_cast(bf16x8, Bs[n * 8 + (ch ^ (n & 7))]);
            }
#pragma unroll
            for (int mt = 0; mt < 4; ++mt)
#pragma unroll
                for (int nt = 0; nt < 4; ++nt)
                    acc[mt][nt] = __builtin_amdgcn_mfma_f32_16x16x32_bf16(
                        af[mt], bfr[nt], acc[mt][nt], 0, 0, 0);
        }
    }

#pragma unroll
    for (int mt = 0; mt < 4; ++mt) {
#pragma unroll
        for (int nt = 0; nt < 4; ++nt) {
#pragma unroll
            for (int r = 0; r < 4; ++r) {
                const int row = m0 + wr + mt * 16 + quad * 4 + r;  // C/D: row=quad*4+r
                const int cc = n0 + wc + nt * 16 + col;            //      col=lane&15
                const float v = acc[mt][nt][r];
                if constexpr (OF32) {
                    ((float*)C)[(size_t)row * N + cc] = v;
                } else if constexpr (!TSTORE) {
                    ((uint16_t*)C)[(size_t)row * N + cc] = f2b(v);
                } else {
                    const int b = row >> 11;        // row = b*S + s
                    const int s = row & (S_ - 1);
                    const int h = cc >> 7;          // cc = h*HD + d
                    const int d = cc & (HD_ - 1);
                    ((uint16_t*)C)[((size_t)((b * NH_ + h) * HD_ + d) << 11) + s] = f2b(v);
                }
            }
        }
    }
}

// Single GEMM (bf16 W). OF32 selects fp32 C (final output).
template <bool TSTORE, bool OF32>
__global__ __launch_bounds__(256, 2) void gemm_bt(const uint16_t* __restrict__ A,
                                                  const uint16_t* __restrict__ W,
                                                  void* __restrict__ C) {
    __shared__ uint4 As[1024];
    __shared__ uint4 Bs[1024];
    const int m0 = blockIdx.y * 128;
    const int n0 = blockIdx.x * 128;
    gemm_body<TSTORE, OF32>(A + (size_t)m0 * H_, W + (size_t)n0 * H_, C, m0, n0, As, Bs);
}

// Fused QKV: blockIdx.z selects weight/output; z==2 (V) uses transposed store.
__global__ __launch_bounds__(256, 2) void gemm_qkv(const uint16_t* __restrict__ A,
                                                   const uint16_t* __restrict__ Wq,
                                                   const uint16_t* __restrict__ Wk,
                                                   const uint16_t* __restrict__ Wv,
                                                   uint16_t* __restrict__ Qb,
                                                   uint16_t* __restrict__ Kb,
                                                   uint16_t* __restrict__ Vt) {
    __shared__ uint4 As[1024];
    __shared__ uint4 Bs[1024];
    const int z = blockIdx.z;
    const int m0 = blockIdx.y * 128;
    const int n0 = blockIdx.x * 128;
    const uint16_t* W = (z == 0) ? Wq : (z == 1) ? Wk : Wv;
    const uint16_t* Ab = A + (size_t)m0 * H_;
    const uint16_t* Wb = W + (size_t)n0 * H_;
    if (z == 2)
        gemm_body<true, false>(Ab, Wb, Vt, m0, n0, As, Bs);
    else
        gemm_body<false, false>(Ab, Wb, (z == 0) ? Qb : Kb, m0, n0, As, Bs);
}

// Legacy fp32-W GEMM (small-ws fallback).
template <bool TSTORE, bool OF32>
__global__ __launch_bounds__(256, 2) void gemm_bt_f32w(const uint16_t* __restrict__ A,
                                                       const float* __restrict__ W,
                                                       void* __restrict__ C) {
    constexpr int K = H_;
    constexpr int N = H_;
    __shared__ uint4 As[1024];
    __shared__ uint4 Bs[1024];
    const int tid = threadIdx.x;
    const int lane = tid & 63;
    const int wave = tid >> 6;
    const int col = lane & 15;
    const int quad = lane >> 4;
    const int m0 = blockIdx.y * 128;
    const int n0 = blockIdx.x * 128;
    const int wr = (wave >> 1) * 64;
    const int wc = (wave & 1) * 64;
    const uint16_t* Abase = A + (size_t)m0 * K;

    floatx4 acc[4][4] = {};
    for (int kb = 0; kb < K; kb += 64) {
        uint4 bv[4];
#pragma unroll
        for (int i = 0; i < 4; ++i) {
            const int L = tid + i * 256;
            const int row = L >> 3;
            const int gch = (L & 7) ^ (row & 7);
            bv[i] = ldrow<true>(W, (size_t)n0 * K + (size_t)row * K + kb + gch * 8);
        }
        __syncthreads();
#pragma unroll
        for (int i = 0; i < 4; ++i) {
            const int L = tid + i * 256;
            const int row = L >> 3;
            const int gch = (L & 7) ^ (row & 7);
            gld_lds16(Abase + (size_t)row * K + kb + gch * 8, &As[i * 256 + wave * 64]);
        }
#pragma unroll
        for (int i = 0; i < 4; ++i) Bs[tid + i * 256] = bv[i];
        __syncthreads();
#pragma unroll
        for (int ks = 0; ks < 2; ++ks) {
            bf16x8 af[4], bfr[4];
            const int ch = ks * 4 + quad;
#pragma unroll
            for (int mt = 0; mt < 4; ++mt) {
                const int m = wr + mt * 16 + col;
                af[mt] = __builtin_bit_cast(bf16x8, As[m * 8 + (ch ^ (m & 7))]);
            }
#pragma unroll
            for (int nt = 0; nt < 4; ++nt) {
                const int n = wc + nt * 16 + col;
                bfr[nt] = __builtin_bit_cast(bf16x8, Bs[n * 8 + (ch ^ (n & 7))]);
            }
#pragma unroll
            for (int mt = 0; mt < 4; ++mt)
#pragma unroll
                for (int nt = 0; nt < 4; ++nt)
                    acc[mt][nt] = __builtin_amdgcn_mfma_f32_16x16x32_bf16(
                        af[mt], bfr[nt], acc[mt][nt], 0, 0, 0);
        }
    }
#pragma unroll
    for (int mt = 0; mt < 4; ++mt)
#pragma unroll
        for (int nt = 0; nt < 4; ++nt)
#pragma unroll
            for (int r = 0; r < 4; ++r) {
                const int row = m0 + wr + mt * 16 + quad * 4 + r;
                const int cc = n0 + wc + nt * 16 + col;
                const float v = acc[mt][nt][r];
                if constexpr (OF32) {
                    ((float*)C)[(size_t)row * N + cc] = v;
                } else if constexpr (!TSTORE) {
                    ((uint16_t*)C)[(size_t)row * N + cc] = f2b(v);
                } else {
                    const int b = row >> 11;
                    const int s = row & (S_ - 1);
                    const int h = cc >> 7;
                    const int d = cc & (HD_ - 1);
                    ((uint16_t*)C)[((size_t)((b * NH_ + h) * HD_ + d) << 11) + s] = f2b(v);
                }
            }
}

// ---------------------------------------------------------------------------
// Blockwise-softmax attention v2: pipelined staging with counted vmcnt.
// Same math/layouts as v1; staging restructured:
//  - Stg = 2 x 16KB ping-pong buffers (64 rows x 16 swizzled chunks each).
//  - Per j-block: 8 quarter-phases (K quarters 0-3: 64 keys x 128 d;
//    V quarters 0-3: 64 d-rows x 128 keys, (half=vq>>1 keys, dq=vq&1 d)).
//  - Phase ph: issue stage(ph+1) -> s_waitcnt vmcnt(4) (stage(ph) landed,
//    prefetch stays in flight; NEVER vmcnt(0) mid-tile) -> raw s_barrier B1
//    (all waves' contributions landed) -> 16 ds_read_b128 + 16 MFMA ->
//    s_barrier B2 (reads done => other slot recyclable next phase).
//  - Raw s_barrier, NOT __syncthreads (which emits vmcnt(0) drain).
//  FIFO audit: every stage = exactly 4 vmem instr/wave; at vmcnt(4) the
//  only younger op is stage(ph+1), so stage(ph) + anything older (aq loads,
//  prior-tile O-stores) is landed. Slot (ph+1)&1 was last read at ph-1,
//  whose reads complete before B2(ph-1) < stage-issue(ph+1). P tiles are
//  per-wave private (no cross-wave sync needed).
// ---------------------------------------------------------------------------
__global__ __launch_bounds__(256, 2) void attn_kernel(const uint16_t* __restrict__ Q,
                                                      const uint16_t* __restrict__ Kp,
                                                      const uint16_t* __restrict__ Vt,
                                                      uint16_t* __restrict__ O) {
    __shared__ uint4 Stg[2048];        // 32 KB: 2 ping-pong buffers of 1024 uint4
    __shared__ uint4 Pl[4 * 16 * 33];  // 33 KB: per-wave P tiles (stride 264)
    const int tid = threadIdx.x;
    const int lane = tid & 63;
    const int wave = tid >> 6;
    const int col = lane & 15;
    const int quad = lane >> 4;

    const int id = blockIdx.x;
    const int xcd = id & 7;
    const int slot = id >> 3;
    const int grp = xcd * 4 + (slot >> 4);  // 0..31
    const int p = slot & 15;
    const int b = grp >> 4;
    const int h = grp & 15;

    const uint16_t* Qb = Q + (size_t)b * S_ * H_ + h * HD_;
    const uint16_t* Kb = Kp + (size_t)b * S_ * H_ + h * HD_;
    const uint16_t* Vb = Vt + (size_t)(b * NH_ + h) * HD_ * S_;
    uint16_t* Ob = O + (size_t)b * S_ * H_ + h * HD_;

    uint16_t* Pw = reinterpret_cast<uint16_t*>(Pl) + wave * 16 * 264;
    const uint4* Pr = Pl + wave * (16 * 33) + col * 33;  // m=col row

    // Stage one 64-row x 16-chunk quarter (16KB), XOR-swizzled, 4 instr/thread.
    auto stage64 = [&](const uint16_t* src, const size_t rstride, uint4* buf) {
#pragma unroll
        for (int i = 0; i < 4; ++i) {
            const int L = tid + i * 256;
            const int row = L >> 4;                 // 0..63
            const int gc = (L & 15) ^ (row & 15);   // involution swizzle
            gld_lds16(src + (size_t)row * rstride + gc * 8, buf + i * 256 + wave * 64);
        }
    };

#pragma unroll
    for (int ti = 0; ti < 2; ++ti) {
        const int t = ti ? (31 - p) : p;   // q-tile (64 rows)
        const int bi = t >> 2;             // 256-block index of these queries
        const int q0 = t * 64 + wave * 16;
        const int nphase = (bi + 1) * 8;

        // Q a-frags: m=lane&15 (query), k = ks*32 + quad*8 + j
        bf16x8 aq[4];
#pragma unroll
        for (int ks = 0; ks < 4; ++ks)
            aq[ks] = ld16(Qb + (size_t)(q0 + col) * H_ + ks * 32 + quad * 8);

        floatx4 o[8] = {};
        floatx4 s[16];

        auto stage_phase = [&](int ph) {
            const int j = ph >> 3, sub = ph & 7;
            uint4* buf = &Stg[(ph & 1) * 1024];
            if (sub < 4) {  // K quarter: 64 key-rows, full d
                stage64(Kb + (size_t)(j * BS_ + sub * 64) * H_, H_, buf);
            } else {        // V quarter: 64 d-rows (dq), 128 keys (half)
                const int vq = sub - 4;
                stage64(Vb + (size_t)((vq & 1) * 64) * S_ + j * BS_ + (vq >> 1) * 128, S_, buf);
            }
        };

        stage_phase(0);
        for (int ph = 0; ph < nphase; ++ph) {
            const int j = ph >> 3;
            const int sub = ph & 7;
            const uint4* buf = &Stg[(ph & 1) * 1024];
            if (ph + 1 < nphase) stage_phase(ph + 1);
            __builtin_amdgcn_sched_barrier(0);
            asm volatile("s_waitcnt vmcnt(4)" ::: "memory");
            __builtin_amdgcn_sched_barrier(0);
            __builtin_amdgcn_s_barrier();  // B1: stage(ph) landed (all waves)
            __builtin_amdgcn_sched_barrier(0);
            if (sub < 4) {
                // ---- scores for key frags sub*4 .. sub*4+3 ----
#pragma unroll
                for (int nf = 0; nf < 4; ++nf) {
                    const int nl = nf * 16 + col;  // local key row
                    floatx4 a = {};
#pragma unroll
                    for (int ks = 0; ks < 4; ++ks) {
                        const bf16x8 kf = __builtin_bit_cast(
                            bf16x8, buf[nl * 16 + ((ks * 4 + quad) ^ (nl & 15))]);
                        a = __builtin_amdgcn_mfma_f32_16x16x32_bf16(aq[ks], kf, a, 0, 0, 0);
                    }
                    s[sub * 4 + nf] = a * SCALE_;
                }
            } else {
                // ---- PV quarter: keys half*128.., d-rows dq*64.. ----
                const int vq = sub - 4;
                const int half = vq >> 1;
                const int dq = vq & 1;
#pragma unroll
                for (int k4 = 0; k4 < 4; ++k4) {
                    const bf16x8 pa =
                        __builtin_bit_cast(bf16x8, Pr[(half * 4 + k4) * 4 + quad]);
#pragma unroll
                    for (int ndl = 0; ndl < 4; ++ndl) {
                        const int nl = ndl * 16 + col;  // local d row
                        const bf16x8 vf = __builtin_bit_cast(
                            bf16x8, buf[nl * 16 + ((k4 * 4 + quad) ^ (nl & 15))]);
                        o[dq * 4 + ndl] = __builtin_amdgcn_mfma_f32_16x16x32_bf16(
                            pa, vf, o[dq * 4 + ndl], 0, 0, 0);
                    }
                }
            }
            __builtin_amdgcn_sched_barrier(0);
            __builtin_amdgcn_s_barrier();  // B2: buf reads done -> recyclable
            __builtin_amdgcn_sched_barrier(0);
            if (sub == 3) {
                // ---- causal mask (diagonal block only) ----
                if (j == bi) {
                    const int qq = (q0 & (BS_ - 1)) + quad * 4;
#pragma unroll
                    for (int nt = 0; nt < 16; ++nt) {
                        const int key = nt * 16 + col;
#pragma unroll
                        for (int r = 0; r < 4; ++r)
                            if (key > qq + r) s[nt][r] = -1e30f;
                    }
                }
                // ---- per-block softmax (no max-sub); row r spans 16 lanes ----
#pragma unroll
                for (int r = 0; r < 4; ++r) {
                    float sm = 0.f;
#pragma unroll
                    for (int nt = 0; nt < 16; ++nt) {
                        const float pw = __expf(s[nt][r]);
                        s[nt][r] = pw;
                        sm += pw;
                    }
#pragma unroll
                    for (int d = 1; d < 16; d <<= 1) sm += __shfl_xor(sm, d);
                    const float inv = 1.0f / sm;
                    const int rowoff = (quad * 4 + r) * 264;
#pragma unroll
                    for (int nt = 0; nt < 16; ++nt)
                        Pw[rowoff + nt * 16 + col] = f2b(s[nt][r] * inv);
                }
            }
        }

        const float rn = 1.0f / ((float)(bi + 1) + 1e-6f);
        // o[dq*4+ndl] holds d = dq*64 + ndl*16 + col
#pragma unroll
        for (int nd = 0; nd < 8; ++nd) {
            const int d = (nd >> 2) * 64 + (nd & 3) * 16 + col;
#pragma unroll
            for (int r = 0; r < 4; ++r)
                Ob[(size_t)(q0 + quad * 4 + r) * H_ + d] = f2b(o[nd][r] * rn);
        }
    }
}

// ---------------------------------------------------------------------------
// d_in: hidden[B,S,H], Wq, Wk, Wv, Wo — fp32. d_out: [B,S,H] fp32.
// d_ws: Xb 16MB | Qb 16 | Kb 16 | Vt 16 (= 64 MB), and if ws_size >= 96MB
// also Wqb|Wkb|Wvb|Wob (4 x 8MB bf16 weights). Ob overlays Xb (dead then).
// ---------------------------------------------------------------------------
extern "C" void kernel_launch(void* const* d_in, const int* in_sizes, int n_in,
                              void* d_out, int out_size, void* d_ws, size_t ws_size,
                              hipStream_t stream) {
    const float* X = (const float*)d_in[0];
    const float* Wq = (const float*)d_in[1];
    const float* Wk = (const float*)d_in[2];
    const float* Wv = (const float*)d_in[3];
    const float* Wo = (const float*)d_in[4];

    const size_t elems = (size_t)B_ * S_ * H_;   // 8M
    const size_t welems = (size_t)H_ * H_;       // 4M
    uint16_t* Xb = (uint16_t*)d_ws;
    uint16_t* Qb = Xb + elems;
    uint16_t* Kb = Qb + elems;
    uint16_t* Vt = Kb + elems;
    uint16_t* Ob = Xb;  // overlay: Xb dead once attn runs
    uint16_t* Wqb = Vt + elems;
    uint16_t* Wkb = Wqb + welems;
    uint16_t* Wvb = Wkb + welems;
    uint16_t* Wob = Wvb + welems;

    const bool bigws = ws_size >= (size_t)96 * 1024 * 1024;

    cvt_kernel<<<(int)(elems / 8 / 256), 256, 0, stream>>>(X, Xb);

    dim3 gg(H_ / 128, (B_ * S_) / 128);  // 16 x 32

    if (bigws) {
        dim3 gw((int)(welems / 8 / 256), 4);
        cvt4_kernel<<<gw, 256, 0, stream>>>(Wq, Wk, Wv, Wo, Wqb, Wkb, Wvb, Wob);
        dim3 gqkv(H_ / 128, (B_ * S_) / 128, 3);  // 1536 wg
        gemm_qkv<<<gqkv, 256, 0, stream>>>(Xb, Wqb, Wkb, Wvb, Qb, Kb, Vt);
        attn_kernel<<<512, 256, 0, stream>>>(Qb, Kb, Vt, Ob);
        gemm_bt<false, true><<<gg, 256, 0, stream>>>(Ob, Wob, d_out);
    } else {
        gemm_bt_f32w<false, false><<<gg, 256, 0, stream>>>(Xb, Wq, Qb);
        gemm_bt_f32w<false, false><<<gg, 256, 0, stream>>>(Xb, Wk, Kb);
        gemm_bt_f32w<true, false><<<gg, 256, 0, stream>>>(Xb, Wv, Vt);
        attn_kernel<<<512, 256, 0, stream>>>(Qb, Kb, Vt, Ob);
        gemm_bt_f32w<false, true><<<gg, 256, 0, stream>>>(Ob, Wo, d_out);
    }
}

// Round 3
// 371.277 us; speedup vs baseline: 1.5197x; 1.5197x over previous
//
#include <hip/hip_runtime.h>
#include <stdint.h>
#include <stddef.h>

// Problem constants: B=2, S=2048, H=2048, NH=16, HD=128, BS=256
constexpr int B_ = 2;
constexpr int S_ = 2048;
constexpr int H_ = 2048;
constexpr int NH_ = 16;
constexpr int HD_ = 128;
constexpr int BS_ = 256;
constexpr float SCALE_ = 0.08838834764831845f;  // 1/sqrt(128)

typedef __bf16 bf16x8 __attribute__((ext_vector_type(8)));
typedef float floatx4 __attribute__((ext_vector_type(4)));
typedef uint16_t u16x8 __attribute__((ext_vector_type(8)));

static __device__ __forceinline__ bf16x8 ld16(const uint16_t* p) {
    return __builtin_bit_cast(bf16x8, *reinterpret_cast<const uint4*>(p));
}
static __device__ __forceinline__ uint16_t f2b(float f) {
    return __builtin_bit_cast(uint16_t, (__bf16)f);  // RNE fptrunc
}

// 8 elems from fp32 (convert) or bf16 source -> packed bf16 uint4.
template <bool F32>
static __device__ __forceinline__ uint4 ldrow(const void* base, size_t eoff) {
    if constexpr (F32) {
        const float* p = (const float*)base + eoff;
        const float4 lo = *reinterpret_cast<const float4*>(p);
        const float4 hi = *reinterpret_cast<const float4*>(p + 4);
        u16x8 k;
        k[0] = f2b(lo.x); k[1] = f2b(lo.y); k[2] = f2b(lo.z); k[3] = f2b(lo.w);
        k[4] = f2b(hi.x); k[5] = f2b(hi.y); k[6] = f2b(hi.z); k[7] = f2b(hi.w);
        return __builtin_bit_cast(uint4, k);
    } else {
        return *reinterpret_cast<const uint4*>((const uint16_t*)base + eoff);
    }
}

// Async global->LDS, 16B per lane. LDS dest = wave-uniform base + lane*16.
static __device__ __forceinline__ void gld_lds16(const uint16_t* g, const uint4* lds_wave_base) {
    __builtin_amdgcn_global_load_lds(
        (const __attribute__((address_space(1))) uint32_t*)g,
        (__attribute__((address_space(3))) uint32_t*)lds_wave_base,
        16, 0, 0);
}

// fp32 -> bf16 pack, 8 elems/thread.
__global__ __launch_bounds__(256) void cvt_kernel(const float* __restrict__ src,
                                                  uint16_t* __restrict__ dst) {
    const size_t i = (size_t)blockIdx.x * 256 + threadIdx.x;
    reinterpret_cast<uint4*>(dst)[i] = ldrow<true>(src, i * 8);
}

// 4 weights in one dispatch (blockIdx.y selects).
__global__ __launch_bounds__(256) void cvt4_kernel(const float* __restrict__ s0,
                                                   const float* __restrict__ s1,
                                                   const float* __restrict__ s2,
                                                   const float* __restrict__ s3,
                                                   uint16_t* __restrict__ d0,
                                                   uint16_t* __restrict__ d1,
                                                   uint16_t* __restrict__ d2,
                                                   uint16_t* __restrict__ d3) {
    const int w = blockIdx.y;
    const float* src = (w == 0) ? s0 : (w == 1) ? s1 : (w == 2) ? s2 : s3;
    uint16_t* dst = (w == 0) ? d0 : (w == 1) ? d1 : (w == 2) ? d2 : d3;
    const size_t i = (size_t)blockIdx.x * 256 + threadIdx.x;
    reinterpret_cast<uint4*>(dst)[i] = ldrow<true>(src, i * 8);
}

// ---------------------------------------------------------------------------
// GEMM core (round-0 structure): C[M x N] = A[M x K] * W[N x K]^T,
// bf16 LDS tiles via async global_load_lds, XOR-swizzled 16B chunks.
// Tile 128x128, BK=64, 4 waves, 32KB LDS -> multi-wg implicit overlap.
// ---------------------------------------------------------------------------
template <bool TSTORE, bool OF32>
static __device__ __forceinline__ void gemm_body(const uint16_t* __restrict__ Abase,
                                                 const uint16_t* __restrict__ Wbase,
                                                 void* __restrict__ C,
                                                 int m0, int n0, uint4* As, uint4* Bs) {
    constexpr int K = H_;
    constexpr int N = H_;
    const int tid = threadIdx.x;
    const int lane = tid & 63;
    const int wave = tid >> 6;
    const int col = lane & 15;
    const int quad = lane >> 4;
    const int wr = (wave >> 1) * 64;
    const int wc = (wave & 1) * 64;

    floatx4 acc[4][4] = {};

    for (int kb = 0; kb < K; kb += 64) {
        __syncthreads();  // prev tile's readers done before LDS overwritten
#pragma unroll
        for (int i = 0; i < 4; ++i) {
            const int L = tid + i * 256;
            const int row = L >> 3;
            const int gch = (L & 7) ^ (row & 7);
            gld_lds16(Abase + (size_t)row * K + kb + gch * 8, &As[i * 256 + wave * 64]);
            gld_lds16(Wbase + (size_t)row * K + kb + gch * 8, &Bs[i * 256 + wave * 64]);
        }
        __syncthreads();  // drains vmcnt (async LDS stores)
#pragma unroll
        for (int ks = 0; ks < 2; ++ks) {
            bf16x8 af[4], bfr[4];
            const int ch = ks * 4 + quad;
#pragma unroll
            for (int mt = 0; mt < 4; ++mt) {
                const int m = wr + mt * 16 + col;
                af[mt] = __builtin_bit_cast(bf16x8, As[m * 8 + (ch ^ (m & 7))]);
            }
#pragma unroll
            for (int nt = 0; nt < 4; ++nt) {
                const int n = wc + nt * 16 + col;
                bfr[nt] = __builtin_bit_cast(bf16x8, Bs[n * 8 + (ch ^ (n & 7))]);
            }
#pragma unroll
            for (int mt = 0; mt < 4; ++mt)
#pragma unroll
                for (int nt = 0; nt < 4; ++nt)
                    acc[mt][nt] = __builtin_amdgcn_mfma_f32_16x16x32_bf16(
                        af[mt], bfr[nt], acc[mt][nt], 0, 0, 0);
        }
    }

#pragma unroll
    for (int mt = 0; mt < 4; ++mt) {
#pragma unroll
        for (int nt = 0; nt < 4; ++nt) {
#pragma unroll
            for (int r = 0; r < 4; ++r) {
                const int row = m0 + wr + mt * 16 + quad * 4 + r;  // C/D: row=quad*4+r
                const int cc = n0 + wc + nt * 16 + col;            //      col=lane&15
                const float v = acc[mt][nt][r];
                if constexpr (OF32) {
                    ((float*)C)[(size_t)row * N + cc] = v;
                } else if constexpr (!TSTORE) {
                    ((uint16_t*)C)[(size_t)row * N + cc] = f2b(v);
                } else {
                    const int b = row >> 11;        // row = b*S + s
                    const int s = row & (S_ - 1);
                    const int h = cc >> 7;          // cc = h*HD + d
                    const int d = cc & (HD_ - 1);
                    ((uint16_t*)C)[((size_t)((b * NH_ + h) * HD_ + d) << 11) + s] = f2b(v);
                }
            }
        }
    }
}

// Single GEMM (bf16 W). OF32 selects fp32 C (final output).
template <bool TSTORE, bool OF32>
__global__ __launch_bounds__(256, 2) void gemm_bt(const uint16_t* __restrict__ A,
                                                  const uint16_t* __restrict__ W,
                                                  void* __restrict__ C) {
    __shared__ uint4 As[1024];
    __shared__ uint4 Bs[1024];
    const int m0 = blockIdx.y * 128;
    const int n0 = blockIdx.x * 128;
    gemm_body<TSTORE, OF32>(A + (size_t)m0 * H_, W + (size_t)n0 * H_, C, m0, n0, As, Bs);
}

// Fused QKV: blockIdx.z selects weight/output; z==2 (V) uses transposed store.
__global__ __launch_bounds__(256, 2) void gemm_qkv(const uint16_t* __restrict__ A,
                                                   const uint16_t* __restrict__ Wq,
                                                   const uint16_t* __restrict__ Wk,
                                                   const uint16_t* __restrict__ Wv,
                                                   uint16_t* __restrict__ Qb,
                                                   uint16_t* __restrict__ Kb,
                                                   uint16_t* __restrict__ Vt) {
    __shared__ uint4 As[1024];
    __shared__ uint4 Bs[1024];
    const int z = blockIdx.z;
    const int m0 = blockIdx.y * 128;
    const int n0 = blockIdx.x * 128;
    const uint16_t* W = (z == 0) ? Wq : (z == 1) ? Wk : Wv;
    const uint16_t* Ab = A + (size_t)m0 * H_;
    const uint16_t* Wb = W + (size_t)n0 * H_;
    if (z == 2)
        gemm_body<true, false>(Ab, Wb, Vt, m0, n0, As, Bs);
    else
        gemm_body<false, false>(Ab, Wb, (z == 0) ? Qb : Kb, m0, n0, As, Bs);
}

// Legacy fp32-W GEMM (small-ws fallback).
template <bool TSTORE, bool OF32>
__global__ __launch_bounds__(256, 2) void gemm_bt_f32w(const uint16_t* __restrict__ A,
                                                       const float* __restrict__ W,
                                                       void* __restrict__ C) {
    constexpr int K = H_;
    constexpr int N = H_;
    __shared__ uint4 As[1024];
    __shared__ uint4 Bs[1024];
    const int tid = threadIdx.x;
    const int lane = tid & 63;
    const int wave = tid >> 6;
    const int col = lane & 15;
    const int quad = lane >> 4;
    const int m0 = blockIdx.y * 128;
    const int n0 = blockIdx.x * 128;
    const int wr = (wave >> 1) * 64;
    const int wc = (wave & 1) * 64;
    const uint16_t* Abase = A + (size_t)m0 * K;

    floatx4 acc[4][4] = {};
    for (int kb = 0; kb < K; kb += 64) {
        uint4 bv[4];
#pragma unroll
        for (int i = 0; i < 4; ++i) {
            const int L = tid + i * 256;
            const int row = L >> 3;
            const int gch = (L & 7) ^ (row & 7);
            bv[i] = ldrow<true>(W, (size_t)n0 * K + (size_t)row * K + kb + gch * 8);
        }
        __syncthreads();
#pragma unroll
        for (int i = 0; i < 4; ++i) {
            const int L = tid + i * 256;
            const int row = L >> 3;
            const int gch = (L & 7) ^ (row & 7);
            gld_lds16(Abase + (size_t)row * K + kb + gch * 8, &As[i * 256 + wave * 64]);
        }
#pragma unroll
        for (int i = 0; i < 4; ++i) Bs[tid + i * 256] = bv[i];
        __syncthreads();
#pragma unroll
        for (int ks = 0; ks < 2; ++ks) {
            bf16x8 af[4], bfr[4];
            const int ch = ks * 4 + quad;
#pragma unroll
            for (int mt = 0; mt < 4; ++mt) {
                const int m = wr + mt * 16 + col;
                af[mt] = __builtin_bit_cast(bf16x8, As[m * 8 + (ch ^ (m & 7))]);
            }
#pragma unroll
            for (int nt = 0; nt < 4; ++nt) {
                const int n = wc + nt * 16 + col;
                bfr[nt] = __builtin_bit_cast(bf16x8, Bs[n * 8 + (ch ^ (n & 7))]);
            }
#pragma unroll
            for (int mt = 0; mt < 4; ++mt)
#pragma unroll
                for (int nt = 0; nt < 4; ++nt)
                    acc[mt][nt] = __builtin_amdgcn_mfma_f32_16x16x32_bf16(
                        af[mt], bfr[nt], acc[mt][nt], 0, 0, 0);
        }
    }
#pragma unroll
    for (int mt = 0; mt < 4; ++mt)
#pragma unroll
        for (int nt = 0; nt < 4; ++nt)
#pragma unroll
            for (int r = 0; r < 4; ++r) {
                const int row = m0 + wr + mt * 16 + quad * 4 + r;
                const int cc = n0 + wc + nt * 16 + col;
                const float v = acc[mt][nt][r];
                if constexpr (OF32) {
                    ((float*)C)[(size_t)row * N + cc] = v;
                } else if constexpr (!TSTORE) {
                    ((uint16_t*)C)[(size_t)row * N + cc] = f2b(v);
                } else {
                    const int b = row >> 11;
                    const int s = row & (S_ - 1);
                    const int h = cc >> 7;
                    const int d = cc & (HD_ - 1);
                    ((uint16_t*)C)[((size_t)((b * NH_ + h) * HD_ + d) << 11) + s] = f2b(v);
                }
            }
}

// ---------------------------------------------------------------------------
// Blockwise-softmax attention v3: pipelined staging, STATIC phase indices.
// Round-2 lesson (rule #20): the runtime phase loop made s[]/o[] runtime-
// indexed -> scratch (VGPR 88, WRITE_SIZE 621MB, 3x slowdown). v3 keeps the
// identical phase schedule but as {runtime j-loop x fully-unrolled 8 subs};
// buffer parity (j*8+sub)&1 == sub&1 is compile-time, all array indices
// static -> registers.
//  - Stg = 2 x 16KB ping-pong buffers (64 rows x 16 swizzled chunks each).
//  - Phase sub: issue stage(next) -> vmcnt(4) (stage(sub) landed, prefetch
//    in flight; vmcnt(0) ONLY on the tail phase — fixes v2's latent race) ->
//    s_barrier B1 -> 16 ds_read_b128 + 16 MFMA (setprio-wrapped, T5) ->
//    s_barrier B2 (reads done => other slot recyclable next phase).
//  - Raw s_barrier, NOT __syncthreads (no vmcnt(0) drain).
//  FIFO audit: stage = exactly 4 vmem instr/wave; at vmcnt(4) the only
//  younger op is stage(next), so stage(sub)+older (aq, prior O-stores) all
//  landed. Slot being staged was last read at phase-2, whose B2 < issue.
// ---------------------------------------------------------------------------
__global__ __launch_bounds__(256, 2) void attn_kernel(const uint16_t* __restrict__ Q,
                                                      const uint16_t* __restrict__ Kp,
                                                      const uint16_t* __restrict__ Vt,
                                                      uint16_t* __restrict__ O) {
    __shared__ uint4 Stg[2048];        // 32 KB: 2 ping-pong buffers of 1024 uint4
    __shared__ uint4 Pl[4 * 16 * 33];  // 33 KB: per-wave P tiles (stride 264)
    const int tid = threadIdx.x;
    const int lane = tid & 63;
    const int wave = tid >> 6;
    const int col = lane & 15;
    const int quad = lane >> 4;

    const int id = blockIdx.x;
    const int xcd = id & 7;
    const int slot = id >> 3;
    const int grp = xcd * 4 + (slot >> 4);  // 0..31
    const int p = slot & 15;
    const int b = grp >> 4;
    const int h = grp & 15;

    const uint16_t* Qb = Q + (size_t)b * S_ * H_ + h * HD_;
    const uint16_t* Kb = Kp + (size_t)b * S_ * H_ + h * HD_;
    const uint16_t* Vb = Vt + (size_t)(b * NH_ + h) * HD_ * S_;
    uint16_t* Ob = O + (size_t)b * S_ * H_ + h * HD_;

    uint16_t* Pw = reinterpret_cast<uint16_t*>(Pl) + wave * 16 * 264;
    const uint4* Pr = Pl + wave * (16 * 33) + col * 33;  // m=col row

    // Stage one 64-row x 16-chunk quarter (16KB), XOR-swizzled, 4 instr/thread.
    auto stage64 = [&](const uint16_t* src, const size_t rstride, uint4* buf) {
#pragma unroll
        for (int i = 0; i < 4; ++i) {
            const int L = tid + i * 256;
            const int row = L >> 4;                 // 0..63
            const int gc = (L & 15) ^ (row & 15);   // involution swizzle
            gld_lds16(src + (size_t)row * rstride + gc * 8, buf + i * 256 + wave * 64);
        }
    };
    // Stage sub-phase `sub` of kv-block `j` into Stg[(sub&1)*1024].
    // Called with compile-time sub only (inlined from unrolled loop).
    auto stage_sub = [&](int j, int sub) {
        uint4* buf = &Stg[(sub & 1) * 1024];
        if (sub < 4) {  // K quarter: 64 key-rows x 128 d
            stage64(Kb + (size_t)(j * BS_ + sub * 64) * H_, H_, buf);
        } else {        // V quarter: 64 d-rows x 128 keys
            const int vq = sub - 4;
            stage64(Vb + (size_t)((vq & 1) * 64) * S_ + j * BS_ + (vq >> 1) * 128, S_, buf);
        }
    };

#pragma unroll
    for (int ti = 0; ti < 2; ++ti) {
        const int t = ti ? (31 - p) : p;   // q-tile (64 rows)
        const int bi = t >> 2;             // 256-block index of these queries
        const int q0 = t * 64 + wave * 16;

        // Q a-frags: m=lane&15 (query), k = ks*32 + quad*8 + j
        bf16x8 aq[4];
#pragma unroll
        for (int ks = 0; ks < 4; ++ks)
            aq[ks] = ld16(Qb + (size_t)(q0 + col) * H_ + ks * 32 + quad * 8);

        floatx4 o[8] = {};
        floatx4 s[16];

        stage_sub(0, 0);
        for (int j = 0; j <= bi; ++j) {
#pragma unroll
            for (int sub = 0; sub < 8; ++sub) {
                const uint4* buf = &Stg[(sub & 1) * 1024];
                if (sub < 7) stage_sub(j, sub + 1);
                else if (j < bi) stage_sub(j + 1, 0);
                __builtin_amdgcn_sched_barrier(0);
                if (sub == 7 && j == bi) {
                    asm volatile("s_waitcnt vmcnt(0)" ::: "memory");  // tail: no prefetch behind
                } else {
                    asm volatile("s_waitcnt vmcnt(4)" ::: "memory");  // stage(sub) landed
                }
                __builtin_amdgcn_sched_barrier(0);
                __builtin_amdgcn_s_barrier();  // B1: all waves' stage(sub) landed
                __builtin_amdgcn_sched_barrier(0);
                if (sub < 4) {
                    // ---- scores for key frags sub*4 .. sub*4+3 ----
                    __builtin_amdgcn_s_setprio(1);
#pragma unroll
                    for (int nf = 0; nf < 4; ++nf) {
                        const int nl = nf * 16 + col;  // local key row
                        floatx4 a = {};
#pragma unroll
                        for (int ks = 0; ks < 4; ++ks) {
                            const bf16x8 kf = __builtin_bit_cast(
                                bf16x8, buf[nl * 16 + ((ks * 4 + quad) ^ (nl & 15))]);
                            a = __builtin_amdgcn_mfma_f32_16x16x32_bf16(aq[ks], kf, a, 0, 0, 0);
                        }
                        s[sub * 4 + nf] = a * SCALE_;
                    }
                    __builtin_amdgcn_s_setprio(0);
                } else {
                    // ---- PV quarter: keys half*128.., d-rows dq*64.. ----
                    const int vq = sub - 4;
                    const int half = vq >> 1;
                    const int dq = vq & 1;
                    __builtin_amdgcn_s_setprio(1);
#pragma unroll
                    for (int k4 = 0; k4 < 4; ++k4) {
                        const bf16x8 pa =
                            __builtin_bit_cast(bf16x8, Pr[(half * 4 + k4) * 4 + quad]);
#pragma unroll
                        for (int ndl = 0; ndl < 4; ++ndl) {
                            const int nl = ndl * 16 + col;  // local d row
                            const bf16x8 vf = __builtin_bit_cast(
                                bf16x8, buf[nl * 16 + ((k4 * 4 + quad) ^ (nl & 15))]);
                            o[dq * 4 + ndl] = __builtin_amdgcn_mfma_f32_16x16x32_bf16(
                                pa, vf, o[dq * 4 + ndl], 0, 0, 0);
                        }
                    }
                    __builtin_amdgcn_s_setprio(0);
                }
                __builtin_amdgcn_sched_barrier(0);
                __builtin_amdgcn_s_barrier();  // B2: buf reads done -> recyclable
                __builtin_amdgcn_sched_barrier(0);
                if (sub == 3) {
                    // ---- causal mask (diagonal block only) ----
                    if (j == bi) {
                        const int qq = (q0 & (BS_ - 1)) + quad * 4;
#pragma unroll
                        for (int nt = 0; nt < 16; ++nt) {
                            const int key = nt * 16 + col;
#pragma unroll
                            for (int r = 0; r < 4; ++r)
                                if (key > qq + r) s[nt][r] = -1e30f;
                        }
                    }
                    // ---- per-block softmax (no max-sub); row r spans 16 lanes ----
#pragma unroll
                    for (int r = 0; r < 4; ++r) {
                        float sm = 0.f;
#pragma unroll
                        for (int nt = 0; nt < 16; ++nt) {
                            const float pw = __expf(s[nt][r]);
                            s[nt][r] = pw;
                            sm += pw;
                        }
#pragma unroll
                        for (int d = 1; d < 16; d <<= 1) sm += __shfl_xor(sm, d);
                        const float inv = 1.0f / sm;
                        const int rowoff = (quad * 4 + r) * 264;
#pragma unroll
                        for (int nt = 0; nt < 16; ++nt)
                            Pw[rowoff + nt * 16 + col] = f2b(s[nt][r] * inv);
                    }
                }
            }
        }

        const float rn = 1.0f / ((float)(bi + 1) + 1e-6f);
        // o[dq*4+ndl] holds d = dq*64 + ndl*16 + col
#pragma unroll
        for (int nd = 0; nd < 8; ++nd) {
            const int d = (nd >> 2) * 64 + (nd & 3) * 16 + col;
#pragma unroll
            for (int r = 0; r < 4; ++r)
                Ob[(size_t)(q0 + quad * 4 + r) * H_ + d] = f2b(o[nd][r] * rn);
        }
    }
}

// ---------------------------------------------------------------------------
// d_in: hidden[B,S,H], Wq, Wk, Wv, Wo — fp32. d_out: [B,S,H] fp32.
// d_ws: Xb 16MB | Qb 16 | Kb 16 | Vt 16 (= 64 MB), and if ws_size >= 96MB
// also Wqb|Wkb|Wvb|Wob (4 x 8MB bf16 weights). Ob overlays Xb (dead then).
// ---------------------------------------------------------------------------
extern "C" void kernel_launch(void* const* d_in, const int* in_sizes, int n_in,
                              void* d_out, int out_size, void* d_ws, size_t ws_size,
                              hipStream_t stream) {
    const float* X = (const float*)d_in[0];
    const float* Wq = (const float*)d_in[1];
    const float* Wk = (const float*)d_in[2];
    const float* Wv = (const float*)d_in[3];
    const float* Wo = (const float*)d_in[4];

    const size_t elems = (size_t)B_ * S_ * H_;   // 8M
    const size_t welems = (size_t)H_ * H_;       // 4M
    uint16_t* Xb = (uint16_t*)d_ws;
    uint16_t* Qb = Xb + elems;
    uint16_t* Kb = Qb + elems;
    uint16_t* Vt = Kb + elems;
    uint16_t* Ob = Xb;  // overlay: Xb dead once attn runs
    uint16_t* Wqb = Vt + elems;
    uint16_t* Wkb = Wqb + welems;
    uint16_t* Wvb = Wkb + welems;
    uint16_t* Wob = Wvb + welems;

    const bool bigws = ws_size >= (size_t)96 * 1024 * 1024;

    cvt_kernel<<<(int)(elems / 8 / 256), 256, 0, stream>>>(X, Xb);

    dim3 gg(H_ / 128, (B_ * S_) / 128);  // 16 x 32

    if (bigws) {
        dim3 gw((int)(welems / 8 / 256), 4);
        cvt4_kernel<<<gw, 256, 0, stream>>>(Wq, Wk, Wv, Wo, Wqb, Wkb, Wvb, Wob);
        dim3 gqkv(H_ / 128, (B_ * S_) / 128, 3);  // 1536 wg
        gemm_qkv<<<gqkv, 256, 0, stream>>>(Xb, Wqb, Wkb, Wvb, Qb, Kb, Vt);
        attn_kernel<<<512, 256, 0, stream>>>(Qb, Kb, Vt, Ob);
        gemm_bt<false, true><<<gg, 256, 0, stream>>>(Ob, Wob, d_out);
    } else {
        gemm_bt_f32w<false, false><<<gg, 256, 0, stream>>>(Xb, Wq, Qb);
        gemm_bt_f32w<false, false><<<gg, 256, 0, stream>>>(Xb, Wk, Kb);
        gemm_bt_f32w<true, false><<<gg, 256, 0, stream>>>(Xb, Wv, Vt);
        attn_kernel<<<512, 256, 0, stream>>>(Qb, Kb, Vt, Ob);
        gemm_bt_f32w<false, true><<<gg, 256, 0, stream>>>(Ob, Wo, d_out);
    }
}

// Round 6
// 346.879 us; speedup vs baseline: 1.6266x; 1.0703x over previous
//
#include <hip/hip_runtime.h>
#include <stdint.h>
#include <stddef.h>

// Problem constants: B=2, S=2048, H=2048, NH=16, HD=128, BS=256
constexpr int B_ = 2;
constexpr int S_ = 2048;
constexpr int H_ = 2048;
constexpr int NH_ = 16;
constexpr int HD_ = 128;
constexpr int BS_ = 256;
constexpr float SCALE_ = 0.08838834764831845f;  // 1/sqrt(128)

typedef __bf16 bf16x8 __attribute__((ext_vector_type(8)));
typedef float floatx4 __attribute__((ext_vector_type(4)));
typedef uint16_t u16x8 __attribute__((ext_vector_type(8)));

static __device__ __forceinline__ bf16x8 ld16(const uint16_t* p) {
    return __builtin_bit_cast(bf16x8, *reinterpret_cast<const uint4*>(p));
}
static __device__ __forceinline__ uint16_t f2b(float f) {
    return __builtin_bit_cast(uint16_t, (__bf16)f);  // RNE fptrunc
}

// 8 elems from fp32 (convert) or bf16 source -> packed bf16 uint4.
template <bool F32>
static __device__ __forceinline__ uint4 ldrow(const void* base, size_t eoff) {
    if constexpr (F32) {
        const float* p = (const float*)base + eoff;
        const float4 lo = *reinterpret_cast<const float4*>(p);
        const float4 hi = *reinterpret_cast<const float4*>(p + 4);
        u16x8 k;
        k[0] = f2b(lo.x); k[1] = f2b(lo.y); k[2] = f2b(lo.z); k[3] = f2b(lo.w);
        k[4] = f2b(hi.x); k[5] = f2b(hi.y); k[6] = f2b(hi.z); k[7] = f2b(hi.w);
        return __builtin_bit_cast(uint4, k);
    } else {
        return *reinterpret_cast<const uint4*>((const uint16_t*)base + eoff);
    }
}

// Async global->LDS, 16B per lane. LDS dest = wave-uniform base + lane*16.
static __device__ __forceinline__ void gld_lds16(const uint16_t* g, const uint4* lds_wave_base) {
    __builtin_amdgcn_global_load_lds(
        (const __attribute__((address_space(1))) uint32_t*)g,
        (__attribute__((address_space(3))) uint32_t*)lds_wave_base,
        16, 0, 0);
}

// fp32 -> bf16 pack, 8 elems/thread.
__global__ __launch_bounds__(256) void cvt_kernel(const float* __restrict__ src,
                                                  uint16_t* __restrict__ dst) {
    const size_t i = (size_t)blockIdx.x * 256 + threadIdx.x;
    reinterpret_cast<uint4*>(dst)[i] = ldrow<true>(src, i * 8);
}

// 4 weights in one dispatch (blockIdx.y selects).
__global__ __launch_bounds__(256) void cvt4_kernel(const float* __restrict__ s0,
                                                   const float* __restrict__ s1,
                                                   const float* __restrict__ s2,
                                                   const float* __restrict__ s3,
                                                   uint16_t* __restrict__ d0,
                                                   uint16_t* __restrict__ d1,
                                                   uint16_t* __restrict__ d2,
                                                   uint16_t* __restrict__ d3) {
    const int w = blockIdx.y;
    const float* src = (w == 0) ? s0 : (w == 1) ? s1 : (w == 2) ? s2 : s3;
    uint16_t* dst = (w == 0) ? d0 : (w == 1) ? d1 : (w == 2) ? d2 : d3;
    const size_t i = (size_t)blockIdx.x * 256 + threadIdx.x;
    reinterpret_cast<uint4*>(dst)[i] = ldrow<true>(src, i * 8);
}

// ---------------------------------------------------------------------------
// GEMM core (round-0 structure, proven): C[M x N] = A[M x K] * W[N x K]^T,
// bf16 LDS tiles via async global_load_lds, XOR-swizzled 16B chunks.
// Tile 128x128, BK=64, 4 waves, 32KB LDS -> multi-wg implicit overlap.
// ---------------------------------------------------------------------------
template <bool TSTORE, bool OF32>
static __device__ __forceinline__ void gemm_body(const uint16_t* __restrict__ Abase,
                                                 const uint16_t* __restrict__ Wbase,
                                                 void* __restrict__ C,
                                                 int m0, int n0, uint4* As, uint4* Bs) {
    constexpr int K = H_;
    constexpr int N = H_;
    const int tid = threadIdx.x;
    const int lane = tid & 63;
    const int wave = tid >> 6;
    const int col = lane & 15;
    const int quad = lane >> 4;
    const int wr = (wave >> 1) * 64;
    const int wc = (wave & 1) * 64;

    floatx4 acc[4][4] = {};

    for (int kb = 0; kb < K; kb += 64) {
        __syncthreads();  // prev tile's readers done before LDS overwritten
#pragma unroll
        for (int i = 0; i < 4; ++i) {
            const int L = tid + i * 256;
            const int row = L >> 3;
            const int gch = (L & 7) ^ (row & 7);
            gld_lds16(Abase + (size_t)row * K + kb + gch * 8, &As[i * 256 + wave * 64]);
            gld_lds16(Wbase + (size_t)row * K + kb + gch * 8, &Bs[i * 256 + wave * 64]);
        }
        __syncthreads();  // drains vmcnt (async LDS stores)
#pragma unroll
        for (int ks = 0; ks < 2; ++ks) {
            bf16x8 af[4], bfr[4];
            const int ch = ks * 4 + quad;
#pragma unroll
            for (int mt = 0; mt < 4; ++mt) {
                const int m = wr + mt * 16 + col;
                af[mt] = __builtin_bit_cast(bf16x8, As[m * 8 + (ch ^ (m & 7))]);
            }
#pragma unroll
            for (int nt = 0; nt < 4; ++nt) {
                const int n = wc + nt * 16 + col;
                bfr[nt] = __builtin_bit_cast(bf16x8, Bs[n * 8 + (ch ^ (n & 7))]);
            }
#pragma unroll
            for (int mt = 0; mt < 4; ++mt)
#pragma unroll
                for (int nt = 0; nt < 4; ++nt)
                    acc[mt][nt] = __builtin_amdgcn_mfma_f32_16x16x32_bf16(
                        af[mt], bfr[nt], acc[mt][nt], 0, 0, 0);
        }
    }

#pragma unroll
    for (int mt = 0; mt < 4; ++mt) {
#pragma unroll
        for (int nt = 0; nt < 4; ++nt) {
#pragma unroll
            for (int r = 0; r < 4; ++r) {
                const int row = m0 + wr + mt * 16 + quad * 4 + r;  // C/D: row=quad*4+r
                const int cc = n0 + wc + nt * 16 + col;            //      col=lane&15
                const float v = acc[mt][nt][r];
                if constexpr (OF32) {
                    ((float*)C)[(size_t)row * N + cc] = v;
                } else if constexpr (!TSTORE) {
                    ((uint16_t*)C)[(size_t)row * N + cc] = f2b(v);
                } else {
                    const int b = row >> 11;        // row = b*S + s
                    const int s = row & (S_ - 1);
                    const int h = cc >> 7;          // cc = h*HD + d
                    const int d = cc & (HD_ - 1);
                    ((uint16_t*)C)[((size_t)((b * NH_ + h) * HD_ + d) << 11) + s] = f2b(v);
                }
            }
        }
    }
}

// Single GEMM (bf16 W). OF32 selects fp32 C (final output).
template <bool TSTORE, bool OF32>
__global__ __launch_bounds__(256, 2) void gemm_bt(const uint16_t* __restrict__ A,
                                                  const uint16_t* __restrict__ W,
                                                  void* __restrict__ C) {
    __shared__ uint4 As[1024];
    __shared__ uint4 Bs[1024];
    const int m0 = blockIdx.y * 128;
    const int n0 = blockIdx.x * 128;
    gemm_body<TSTORE, OF32>(A + (size_t)m0 * H_, W + (size_t)n0 * H_, C, m0, n0, As, Bs);
}

// Fused QKV: blockIdx.z selects weight/output; z==2 (V) uses transposed store.
__global__ __launch_bounds__(256, 2) void gemm_qkv(const uint16_t* __restrict__ A,
                                                   const uint16_t* __restrict__ Wq,
                                                   const uint16_t* __restrict__ Wk,
                                                   const uint16_t* __restrict__ Wv,
                                                   uint16_t* __restrict__ Qb,
                                                   uint16_t* __restrict__ Kb,
                                                   uint16_t* __restrict__ Vt) {
    __shared__ uint4 As[1024];
    __shared__ uint4 Bs[1024];
    const int z = blockIdx.z;
    const int m0 = blockIdx.y * 128;
    const int n0 = blockIdx.x * 128;
    const uint16_t* W = (z == 0) ? Wq : (z == 1) ? Wk : Wv;
    const uint16_t* Ab = A + (size_t)m0 * H_;
    const uint16_t* Wb = W + (size_t)n0 * H_;
    if (z == 2)
        gemm_body<true, false>(Ab, Wb, Vt, m0, n0, As, Bs);
    else
        gemm_body<false, false>(Ab, Wb, (z == 0) ? Qb : Kb, m0, n0, As, Bs);
}

// Legacy fp32-W GEMM (small-ws fallback).
template <bool TSTORE, bool OF32>
__global__ __launch_bounds__(256, 2) void gemm_bt_f32w(const uint16_t* __restrict__ A,
                                                       const float* __restrict__ W,
                                                       void* __restrict__ C) {
    constexpr int K = H_;
    constexpr int N = H_;
    __shared__ uint4 As[1024];
    __shared__ uint4 Bs[1024];
    const int tid = threadIdx.x;
    const int lane = tid & 63;
    const int wave = tid >> 6;
    const int col = lane & 15;
    const int quad = lane >> 4;
    const int m0 = blockIdx.y * 128;
    const int n0 = blockIdx.x * 128;
    const int wr = (wave >> 1) * 64;
    const int wc = (wave & 1) * 64;
    const uint16_t* Abase = A + (size_t)m0 * K;

    floatx4 acc[4][4] = {};
    for (int kb = 0; kb < K; kb += 64) {
        uint4 bv[4];
#pragma unroll
        for (int i = 0; i < 4; ++i) {
            const int L = tid + i * 256;
            const int row = L >> 3;
            const int gch = (L & 7) ^ (row & 7);
            bv[i] = ldrow<true>(W, (size_t)n0 * K + (size_t)row * K + kb + gch * 8);
        }
        __syncthreads();
#pragma unroll
        for (int i = 0; i < 4; ++i) {
            const int L = tid + i * 256;
            const int row = L >> 3;
            const int gch = (L & 7) ^ (row & 7);
            gld_lds16(Abase + (size_t)row * K + kb + gch * 8, &As[i * 256 + wave * 64]);
        }
#pragma unroll
        for (int i = 0; i < 4; ++i) Bs[tid + i * 256] = bv[i];
        __syncthreads();
#pragma unroll
        for (int ks = 0; ks < 2; ++ks) {
            bf16x8 af[4], bfr[4];
            const int ch = ks * 4 + quad;
#pragma unroll
            for (int mt = 0; mt < 4; ++mt) {
                const int m = wr + mt * 16 + col;
                af[mt] = __builtin_bit_cast(bf16x8, As[m * 8 + (ch ^ (m & 7))]);
            }
#pragma unroll
            for (int nt = 0; nt < 4; ++nt) {
                const int n = wc + nt * 16 + col;
                bfr[nt] = __builtin_bit_cast(bf16x8, Bs[n * 8 + (ch ^ (n & 7))]);
            }
#pragma unroll
            for (int mt = 0; mt < 4; ++mt)
#pragma unroll
                for (int nt = 0; nt < 4; ++nt)
                    acc[mt][nt] = __builtin_amdgcn_mfma_f32_16x16x32_bf16(
                        af[mt], bfr[nt], acc[mt][nt], 0, 0, 0);
        }
    }
#pragma unroll
    for (int mt = 0; mt < 4; ++mt)
#pragma unroll
        for (int nt = 0; nt < 4; ++nt)
#pragma unroll
            for (int r = 0; r < 4; ++r) {
                const int row = m0 + wr + mt * 16 + quad * 4 + r;
                const int cc = n0 + wc + nt * 16 + col;
                const float v = acc[mt][nt][r];
                if constexpr (OF32) {
                    ((float*)C)[(size_t)row * N + cc] = v;
                } else if constexpr (!TSTORE) {
                    ((uint16_t*)C)[(size_t)row * N + cc] = f2b(v);
                } else {
                    const int b = row >> 11;
                    const int s = row & (S_ - 1);
                    const int h = cc >> 7;
                    const int d = cc & (HD_ - 1);
                    ((uint16_t*)C)[((size_t)((b * NH_ + h) * HD_ + d) << 11) + s] = f2b(v);
                }
            }
}

// ---------------------------------------------------------------------------
// Blockwise-softmax attention v1 (round-0 proven structure) + T5 setprio.
// __syncthreads-based staging (race-free by construction; counted-vmcnt
// variants v2-v4 abandoned: racy window + measured slower).
// setprio(1) wraps the QK and PV MFMA clusters (m191: +4-7% on attn with
// independent wgs; 2 wg/CU here run at different phases).
// ---------------------------------------------------------------------------
__global__ __launch_bounds__(256, 2) void attn_kernel(const uint16_t* __restrict__ Q,
                                                      const uint16_t* __restrict__ Kp,
                                                      const uint16_t* __restrict__ Vt,
                                                      uint16_t* __restrict__ O) {
    __shared__ uint4 Stg[2048];        // 32 KB: 128 rows x 16 chunks
    __shared__ uint4 Pl[4 * 16 * 33];  // 33 KB: per-wave P tiles (stride 264)
    const int tid = threadIdx.x;
    const int lane = tid & 63;
    const int wave = tid >> 6;
    const int col = lane & 15;
    const int quad = lane >> 4;

    const int id = blockIdx.x;
    const int xcd = id & 7;
    const int slot = id >> 3;
    const int grp = xcd * 4 + (slot >> 4);  // 0..31
    const int p = slot & 15;
    const int b = grp >> 4;
    const int h = grp & 15;

    const uint16_t* Qb = Q + (size_t)b * S_ * H_ + h * HD_;
    const uint16_t* Kb = Kp + (size_t)b * S_ * H_ + h * HD_;
    const uint16_t* Vb = Vt + (size_t)(b * NH_ + h) * HD_ * S_;
    uint16_t* Ob = O + (size_t)b * S_ * H_ + h * HD_;

    uint16_t* Pw = reinterpret_cast<uint16_t*>(Pl) + wave * 16 * 264;
    const uint4* Pr = Pl + wave * (16 * 33) + col * 33;  // m=col row

#pragma unroll
    for (int ti = 0; ti < 2; ++ti) {
        const int t = ti ? (31 - p) : p;   // q-tile (64 rows)
        const int bi = t >> 2;             // 256-block index of these queries
        const int q0 = t * 64 + wave * 16;

        // Q a-frags: m=lane&15 (query), k = ks*32 + quad*8 + j
        bf16x8 aq[4];
#pragma unroll
        for (int ks = 0; ks < 4; ++ks)
            aq[ks] = ld16(Qb + (size_t)(q0 + col) * H_ + ks * 32 + quad * 8);

        floatx4 o[8] = {};

        for (int j = 0; j <= bi; ++j) {
            floatx4 s[16];
            // ---- scores: two staged K halves (128 keys x 128 d each) ----
#pragma unroll
            for (int half = 0; half < 2; ++half) {
                __syncthreads();  // prior stage's consumers done
                const uint16_t* src = Kb + (size_t)(j * BS_ + half * 128) * H_;
#pragma unroll
                for (int i = 0; i < 8; ++i) {
                    const int L = tid + i * 256;
                    const int row = L >> 4;
                    const int gc = (L & 15) ^ (row & 15);
                    gld_lds16(src + (size_t)row * H_ + gc * 8, &Stg[i * 256 + wave * 64]);
                }
                __syncthreads();  // drain async stores; stage visible
                __builtin_amdgcn_s_setprio(1);
#pragma unroll
                for (int nt8 = 0; nt8 < 8; ++nt8) {
                    const int n = nt8 * 16 + col;  // key row (B-frag n=lane&15)
                    floatx4 a = {};
#pragma unroll
                    for (int ks = 0; ks < 4; ++ks) {
                        const bf16x8 kf = __builtin_bit_cast(
                            bf16x8, Stg[n * 16 + ((ks * 4 + quad) ^ (n & 15))]);
                        a = __builtin_amdgcn_mfma_f32_16x16x32_bf16(aq[ks], kf, a, 0, 0, 0);
                    }
                    s[half * 8 + nt8] = a * SCALE_;
                }
                __builtin_amdgcn_s_setprio(0);
            }
            // ---- causal mask (diagonal block only) ----
            if (j == bi) {
                const int qq = (q0 & (BS_ - 1)) + quad * 4;
#pragma unroll
                for (int nt = 0; nt < 16; ++nt) {
                    const int key = nt * 16 + col;
#pragma unroll
                    for (int r = 0; r < 4; ++r)
                        if (key > qq + r) s[nt][r] = -1e30f;
                }
            }
            // ---- per-block softmax (no max-sub); row r spans 16 lanes ----
#pragma unroll
            for (int r = 0; r < 4; ++r) {
                float sm = 0.f;
#pragma unroll
                for (int nt = 0; nt < 16; ++nt) {
                    const float pw = __expf(s[nt][r]);
                    s[nt][r] = pw;
                    sm += pw;
                }
#pragma unroll
                for (int d = 1; d < 16; d <<= 1) sm += __shfl_xor(sm, d);
                const float inv = 1.0f / sm;
                const int rowoff = (quad * 4 + r) * 264;
#pragma unroll
                for (int nt = 0; nt < 16; ++nt)
                    Pw[rowoff + nt * 16 + col] = f2b(s[nt][r] * inv);
            }
            // ---- PV: two staged V halves (128 d-rows x 128 keys each) ----
#pragma unroll
            for (int half = 0; half < 2; ++half) {
                __syncthreads();  // score reads (and prior PV reads) done
                const uint16_t* src = Vb + j * BS_ + half * 128;
#pragma unroll
                for (int i = 0; i < 8; ++i) {
                    const int L = tid + i * 256;
                    const int row = L >> 4;
                    const int gc = (L & 15) ^ (row & 15);
                    gld_lds16(src + (size_t)row * S_ + gc * 8, &Stg[i * 256 + wave * 64]);
                }
                __syncthreads();
                __builtin_amdgcn_s_setprio(1);
#pragma unroll
                for (int k4 = 0; k4 < 4; ++k4) {
                    const bf16x8 pa =
                        __builtin_bit_cast(bf16x8, Pr[(half * 4 + k4) * 4 + quad]);
#pragma unroll
                    for (int nd = 0; nd < 8; ++nd) {
                        const int n = nd * 16 + col;  // d row (B-frag n=lane&15)
                        const bf16x8 vf = __builtin_bit_cast(
                            bf16x8, Stg[n * 16 + ((k4 * 4 + quad) ^ (n & 15))]);
                        o[nd] = __builtin_amdgcn_mfma_f32_16x16x32_bf16(pa, vf, o[nd], 0, 0, 0);
                    }
                }
                __builtin_amdgcn_s_setprio(0);
            }
        }

        const float rn = 1.0f / ((float)(bi + 1) + 1e-6f);
#pragma unroll
        for (int nd = 0; nd < 8; ++nd)
#pragma unroll
            for (int r = 0; r < 4; ++r)
                Ob[(size_t)(q0 + quad * 4 + r) * H_ + nd * 16 + col] = f2b(o[nd][r] * rn);
    }
}

// ---------------------------------------------------------------------------
// d_in: hidden[B,S,H], Wq, Wk, Wv, Wo — fp32. d_out: [B,S,H] fp32.
// d_ws: Xb 16MB | Qb 16 | Kb 16 | Vt 16 (= 64 MB), and if ws_size >= 96MB
// also Wqb|Wkb|Wvb|Wob (4 x 8MB bf16 weights). Ob overlays Xb (dead then).
// ---------------------------------------------------------------------------
extern "C" void kernel_launch(void* const* d_in, const int* in_sizes, int n_in,
                              void* d_out, int out_size, void* d_ws, size_t ws_size,
                              hipStream_t stream) {
    const float* X = (const float*)d_in[0];
    const float* Wq = (const float*)d_in[1];
    const float* Wk = (const float*)d_in[2];
    const float* Wv = (const float*)d_in[3];
    const float* Wo = (const float*)d_in[4];

    const size_t elems = (size_t)B_ * S_ * H_;   // 8M
    const size_t welems = (size_t)H_ * H_;       // 4M
    uint16_t* Xb = (uint16_t*)d_ws;
    uint16_t* Qb = Xb + elems;
    uint16_t* Kb = Qb + elems;
    uint16_t* Vt = Kb + elems;
    uint16_t* Ob = Xb;  // overlay: Xb dead once attn runs
    uint16_t* Wqb = Vt + elems;
    uint16_t* Wkb = Wqb + welems;
    uint16_t* Wvb = Wkb + welems;
    uint16_t* Wob = Wvb + welems;

    const bool bigws = ws_size >= (size_t)96 * 1024 * 1024;

    cvt_kernel<<<(int)(elems / 8 / 256), 256, 0, stream>>>(X, Xb);

    dim3 gg(H_ / 128, (B_ * S_) / 128);  // 16 x 32

    if (bigws) {
        dim3 gw((int)(welems / 8 / 256), 4);
        cvt4_kernel<<<gw, 256, 0, stream>>>(Wq, Wk, Wv, Wo, Wqb, Wkb, Wvb, Wob);
        dim3 gqkv(H_ / 128, (B_ * S_) / 128, 3);  // 1536 wg
        gemm_qkv<<<gqkv, 256, 0, stream>>>(Xb, Wqb, Wkb, Wvb, Qb, Kb, Vt);
        attn_kernel<<<512, 256, 0, stream>>>(Qb, Kb, Vt, Ob);
        gemm_bt<false, true><<<gg, 256, 0, stream>>>(Ob, Wob, d_out);
    } else {
        gemm_bt_f32w<false, false><<<gg, 256, 0, stream>>>(Xb, Wq, Qb);
        gemm_bt_f32w<false, false><<<gg, 256, 0, stream>>>(Xb, Wk, Kb);
        gemm_bt_f32w<true, false><<<gg, 256, 0, stream>>>(Xb, Wv, Vt);
        attn_kernel<<<512, 256, 0, stream>>>(Qb, Kb, Vt, Ob);
        gemm_bt_f32w<false, true><<<gg, 256, 0, stream>>>(Ob, Wo, d_out);
    }
}